// Round 1
// baseline (100.571 us; speedup 1.0000x reference)
//
#include <hip/hip_runtime.h>

#define NB 4
#define DD 128
#define NN 4096
#define INV_T 14.285714285714285f

typedef __attribute__((ext_vector_type(8))) short bf16x8;
typedef __attribute__((ext_vector_type(4))) float f32x4;

static __device__ __forceinline__ unsigned short f32_to_bf16(float x){
  unsigned u = __float_as_uint(x);
  u += 0x7fffu + ((u >> 16) & 1u);   // RNE
  return (unsigned short)(u >> 16);
}

// Kernel A: L1-normalize + transpose [B][128][N] fp32 -> [B][N][128] bf16
__global__ __launch_bounds__(256) void norm_kernel(const float* __restrict__ fq,
                                                   const float* __restrict__ fk,
                                                   unsigned short* __restrict__ qn,
                                                   unsigned short* __restrict__ kn){
  const float* src = blockIdx.z ? fk : fq;
  unsigned short* dst = blockIdx.z ? kn : qn;
  int b = blockIdx.y;
  int n0 = blockIdx.x * 64;
  __shared__ float sT[64][129];   // stride 129: conflict-free col writes/row reads
  __shared__ float red[4][64];
  __shared__ float srd[64];
  int t = threadIdx.x;
  const float* sb = src + (size_t)b*DD*NN + n0;
  #pragma unroll
  for (int it = 0; it < 32; ++it){
    int idx = it*256 + t;
    int d = idx >> 6, nn = idx & 63;
    sT[nn][d] = sb[(size_t)d*NN + nn];       // coalesced 256B per d-row
  }
  __syncthreads();
  {
    int nn = t & 63, part = t >> 6;
    float s = 0.f;
    #pragma unroll
    for (int j = 0; j < 32; ++j) s += fabsf(sT[nn][part*32 + j]);
    red[part][nn] = s;
  }
  __syncthreads();
  if (t < 64){
    float dsum = red[0][t] + red[1][t] + red[2][t] + red[3][t];
    srd[t] = 1.f / fmaxf(dsum, 1e-12f);
  }
  __syncthreads();
  unsigned short* db = dst + ((size_t)b*NN + n0)*DD;
  #pragma unroll
  for (int it = 0; it < 4; ++it){
    int c = it*256 + t;
    int row = c >> 4, dc = c & 15;
    float r = srd[row];
    unsigned v[4];
    #pragma unroll
    for (int p = 0; p < 4; ++p){
      unsigned short lo = f32_to_bf16(sT[row][dc*8 + p*2    ] * r);
      unsigned short hi = f32_to_bf16(sT[row][dc*8 + p*2 + 1] * r);
      v[p] = (unsigned)lo | ((unsigned)hi << 16);
    }
    uint4 pack = make_uint4(v[0], v[1], v[2], v[3]);
    *reinterpret_cast<uint4*>(db + (size_t)row*DD + dc*8) = pack;   // coalesced
  }
}

// Kernel B: sim = qn . kn^T tilewise (bf16 MFMA), rowsum += sum_cols exp(sim/T)
// block tile 128 rows x 1024 cols (8 k-tiles of 128), grid (32, 4, B)
__global__ __launch_bounds__(256,2) void simexp_kernel(const unsigned short* __restrict__ qn,
                                                       const unsigned short* __restrict__ kn,
                                                       float* __restrict__ rowsum){
  __shared__ uint4 smem[4096];   // 64 KB: sQ [0,2048), sK [2048,4096)
  uint4* sQ = smem;
  uint4* sK = smem + 2048;
  int t = threadIdx.x;
  int w = t >> 6, lane = t & 63;
  int quad = lane >> 4, l16 = lane & 15;
  int b  = blockIdx.z;
  int r0 = blockIdx.x * 128;
  int c0 = blockIdx.y * 1024;
  const uint4* gq = reinterpret_cast<const uint4*>(qn + ((size_t)b*NN + r0)*DD);
  const uint4* gk = reinterpret_cast<const uint4*>(kn + ((size_t)b*NN + c0)*DD);
  // stage q-tile 128x128 bf16 (32 KB), XOR-swizzled 16B chunks
  #pragma unroll
  for (int it = 0; it < 8; ++it){
    int c = it*256 + t;
    int row = c >> 4, dl = c & 15;
    sQ[row*16 + (dl ^ (row & 15))] = gq[c];
  }
  __syncthreads();
  int wr = (w >> 1)*64, wc = (w & 1)*64;   // wave quadrant
  // a-frags register-resident: rows wr+i*16+l16, k = ks*32 + quad*8 + 0..7
  bf16x8 a[4][4];
  #pragma unroll
  for (int i = 0; i < 4; ++i){
    int row = wr + i*16 + l16;
    #pragma unroll
    for (int ks = 0; ks < 4; ++ks)
      a[i][ks] = __builtin_bit_cast(bf16x8, sQ[row*16 + ((ks*4 + quad) ^ l16)]);
  }
  float rsum[16];
  #pragma unroll
  for (int s = 0; s < 16; ++s) rsum[s] = 0.f;

  for (int kt = 0; kt < 8; ++kt){
    __syncthreads();
    #pragma unroll
    for (int it = 0; it < 8; ++it){
      int c = it*256 + t;
      int row = c >> 4, dl = c & 15;
      sK[row*16 + (dl ^ (row & 15))] = gk[kt*2048 + c];
    }
    __syncthreads();
    f32x4 acc[4][4];
    #pragma unroll
    for (int i = 0; i < 4; ++i)
      #pragma unroll
      for (int j = 0; j < 4; ++j)
        acc[i][j] = (f32x4){0.f, 0.f, 0.f, 0.f};
    #pragma unroll
    for (int ks = 0; ks < 4; ++ks){
      bf16x8 bfr[4];
      #pragma unroll
      for (int j = 0; j < 4; ++j){
        int col = wc + j*16 + l16;
        bfr[j] = __builtin_bit_cast(bf16x8, sK[col*16 + ((ks*4 + quad) ^ l16)]);
      }
      #pragma unroll
      for (int i = 0; i < 4; ++i)
        #pragma unroll
        for (int j = 0; j < 4; ++j)
          acc[i][j] = __builtin_amdgcn_mfma_f32_16x16x32_bf16(a[i][ks], bfr[j], acc[i][j], 0, 0, 0);
    }
    // epilogue: C[row=i*16+quad*4+r][col=j*16+l16]
    #pragma unroll
    for (int i = 0; i < 4; ++i)
      #pragma unroll
      for (int j = 0; j < 4; ++j)
        #pragma unroll
        for (int r = 0; r < 4; ++r)
          rsum[i*4 + r] += __expf(acc[i][j][r] * INV_T);
  }
  // reduce over the 16 cols (l16 lanes) per quad, then atomic per row
  #pragma unroll
  for (int s = 0; s < 16; ++s){
    float v = rsum[s];
    v += __shfl_xor(v, 1, 64);
    v += __shfl_xor(v, 2, 64);
    v += __shfl_xor(v, 4, 64);
    v += __shfl_xor(v, 8, 64);
    if (l16 == 0){
      int row = r0 + wr + (s >> 2)*16 + quad*4 + (s & 3);
      atomicAdd(&rowsum[b*NN + row], v);
    }
  }
}

// Kernel C: subtract diag exp, log1p, mean
__global__ __launch_bounds__(256) void finalize_kernel(const unsigned short* __restrict__ qn,
                                                       const unsigned short* __restrict__ kn,
                                                       const float* __restrict__ rowsum,
                                                       float* __restrict__ out){
  int idx = blockIdx.x*256 + threadIdx.x;   // 0..16383 = b*N + n
  const uint4* q = reinterpret_cast<const uint4*>(qn + (size_t)idx*DD);
  const uint4* k = reinterpret_cast<const uint4*>(kn + (size_t)idx*DD);
  float dot = 0.f;
  #pragma unroll
  for (int c = 0; c < 16; ++c){
    uint4 uq = q[c], uk = k[c];
    unsigned aq[4] = {uq.x, uq.y, uq.z, uq.w};
    unsigned ak[4] = {uk.x, uk.y, uk.z, uk.w};
    #pragma unroll
    for (int p = 0; p < 4; ++p){
      float q0 = __uint_as_float(aq[p] << 16);
      float q1 = __uint_as_float(aq[p] & 0xffff0000u);
      float k0 = __uint_as_float(ak[p] << 16);
      float k1 = __uint_as_float(ak[p] & 0xffff0000u);
      dot = fmaf(q0, k0, dot);
      dot = fmaf(q1, k1, dot);
    }
  }
  float diag = __expf(dot * INV_T);
  float loss = log1pf(rowsum[idx] - diag);
  loss += __shfl_xor(loss, 1, 64);
  loss += __shfl_xor(loss, 2, 64);
  loss += __shfl_xor(loss, 4, 64);
  loss += __shfl_xor(loss, 8, 64);
  loss += __shfl_xor(loss, 16, 64);
  loss += __shfl_xor(loss, 32, 64);
  if ((threadIdx.x & 63) == 0)
    atomicAdd(out, loss * (1.f / (float)(NB*NN)));
}

extern "C" void kernel_launch(void* const* d_in, const int* in_sizes, int n_in,
                              void* d_out, int out_size, void* d_ws, size_t ws_size,
                              hipStream_t stream){
  const float* fq = (const float*)d_in[0];
  const float* fk = (const float*)d_in[1];
  unsigned short* qn = (unsigned short*)d_ws;                  // 4 MB bf16 [B][N][D]
  unsigned short* kn = qn + (size_t)NB*NN*DD;                  // 4 MB
  float* rowsum = (float*)(kn + (size_t)NB*NN*DD);             // 64 KB
  float* out = (float*)d_out;

  hipMemsetAsync(rowsum, 0, (size_t)NB*NN*sizeof(float), stream);
  hipMemsetAsync(out, 0, sizeof(float), stream);

  norm_kernel<<<dim3(NN/64, NB, 2), 256, 0, stream>>>(fq, fk, qn, kn);
  simexp_kernel<<<dim3(NN/128, 4, NB), 256, 0, stream>>>(qn, kn, rowsum);
  finalize_kernel<<<dim3(NB*NN/256), 256, 0, stream>>>(qn, kn, rowsum, out);
}

// Round 2
// 98.596 us; speedup vs baseline: 1.0200x; 1.0200x over previous
//
#include <hip/hip_runtime.h>

#define NB 4
#define DD 128
#define NN 4096
#define INV_T 14.285714285714285f

typedef __attribute__((ext_vector_type(8))) short bf16x8;
typedef __attribute__((ext_vector_type(4))) float f32x4;

static __device__ __forceinline__ unsigned short f32_to_bf16(float x){
  unsigned u = __float_as_uint(x);
  u += 0x7fffu + ((u >> 16) & 1u);   // RNE
  return (unsigned short)(u >> 16);
}

// async 16B global->LDS DMA (lds dest must be wave-uniform; lands at +lane*16)
static __device__ __forceinline__ void async_copy16(const uint4* g, uint4* l){
  __builtin_amdgcn_global_load_lds(
      (const __attribute__((address_space(1))) unsigned int*)g,
      (__attribute__((address_space(3))) unsigned int*)l, 16, 0, 0);
}

// Kernel A: L1-normalize + transpose [B][128][N] fp32 -> [B][N][128] bf16
// NOTE: 16B chunks are stored XOR-swizzled within each row: true chunk c of
// row r lands at slot c ^ (r&15). This makes a *linear* global_load_lds copy
// in simexp produce the bank-conflict-free swizzled LDS layout directly.
// finalize is unaffected (same permutation on q and k => dot invariant).
__global__ __launch_bounds__(256) void norm_kernel(const float* __restrict__ fq,
                                                   const float* __restrict__ fk,
                                                   unsigned short* __restrict__ qn,
                                                   unsigned short* __restrict__ kn){
  const float* src = blockIdx.z ? fk : fq;
  unsigned short* dst = blockIdx.z ? kn : qn;
  int b = blockIdx.y;
  int n0 = blockIdx.x * 64;
  __shared__ float sT[64][129];   // stride 129: conflict-free col writes/row reads
  __shared__ float red[4][64];
  __shared__ float srd[64];
  int t = threadIdx.x;
  const float* sb = src + (size_t)b*DD*NN + n0;
  #pragma unroll
  for (int it = 0; it < 32; ++it){
    int idx = it*256 + t;
    int d = idx >> 6, nn = idx & 63;
    sT[nn][d] = sb[(size_t)d*NN + nn];       // coalesced 256B per d-row
  }
  __syncthreads();
  {
    int nn = t & 63, part = t >> 6;
    float s = 0.f;
    #pragma unroll
    for (int j = 0; j < 32; ++j) s += fabsf(sT[nn][part*32 + j]);
    red[part][nn] = s;
  }
  __syncthreads();
  if (t < 64){
    float dsum = red[0][t] + red[1][t] + red[2][t] + red[3][t];
    srd[t] = 1.f / fmaxf(dsum, 1e-12f);
  }
  __syncthreads();
  unsigned short* db = dst + ((size_t)b*NN + n0)*DD;
  #pragma unroll
  for (int it = 0; it < 4; ++it){
    int c = it*256 + t;
    int row = c >> 4, dc = c & 15;
    float r = srd[row];
    unsigned v[4];
    #pragma unroll
    for (int p = 0; p < 4; ++p){
      unsigned short lo = f32_to_bf16(sT[row][dc*8 + p*2    ] * r);
      unsigned short hi = f32_to_bf16(sT[row][dc*8 + p*2 + 1] * r);
      v[p] = (unsigned)lo | ((unsigned)hi << 16);
    }
    uint4 pack = make_uint4(v[0], v[1], v[2], v[3]);
    int sw = dc ^ (row & 15);     // global pre-swizzle (row & 15 == global row & 15)
    *reinterpret_cast<uint4*>(db + (size_t)row*DD + sw*8) = pack;   // still contiguous 1KB/wave
  }
}

// Kernel B: sim = qn . kn^T tilewise (bf16 MFMA), rowsum += sum_cols exp(sim/T)
// block tile 128 rows x 1024 cols (8 k-tiles of 128), grid (32, 4, B)
// staging via global_load_lds dwordx4 (m97 structure)
__global__ __launch_bounds__(256,2) void simexp_kernel(const unsigned short* __restrict__ qn,
                                                       const unsigned short* __restrict__ kn,
                                                       float* __restrict__ rowsum){
  __shared__ uint4 sQ[2048];   // 32 KB
  __shared__ uint4 sK[2048];   // 32 KB
  int t = threadIdx.x;
  int w = t >> 6, lane = t & 63;
  int quad = lane >> 4, l16 = lane & 15;
  int b  = blockIdx.z;
  int r0 = blockIdx.x * 128;
  int c0 = blockIdx.y * 1024;
  const uint4* gq = reinterpret_cast<const uint4*>(qn + ((size_t)b*NN + r0)*DD);
  const uint4* gk = reinterpret_cast<const uint4*>(kn + ((size_t)b*NN + c0)*DD);
  // async stage Q tile + K tile 0 (global data already swizzle-laid-out)
  #pragma unroll
  for (int i = 0; i < 8; ++i)
    async_copy16(gq + w*512 + i*64 + lane, &sQ[w*512 + i*64]);
  #pragma unroll
  for (int i = 0; i < 8; ++i)
    async_copy16(gk + w*512 + i*64 + lane, &sK[w*512 + i*64]);
  __syncthreads();

  int wr = (w >> 1)*64, wc = (w & 1)*64;   // wave quadrant
  // a-frags register-resident: rows wr+i*16+l16, k-chunk ks*4+quad (deswizzle by ^l16)
  bf16x8 a[4][4];
  #pragma unroll
  for (int i = 0; i < 4; ++i){
    int row = wr + i*16 + l16;
    #pragma unroll
    for (int ks = 0; ks < 4; ++ks)
      a[i][ks] = __builtin_bit_cast(bf16x8, sQ[row*16 + ((ks*4 + quad) ^ l16)]);
  }
  float rsum[16];
  #pragma unroll
  for (int s = 0; s < 16; ++s) rsum[s] = 0.f;

  for (int kt = 0; kt < 8; ++kt){
    if (kt){
      __syncthreads();
      #pragma unroll
      for (int i = 0; i < 8; ++i)
        async_copy16(gk + kt*2048 + w*512 + i*64 + lane, &sK[w*512 + i*64]);
      __syncthreads();
    }
    f32x4 acc[4][4];
    #pragma unroll
    for (int i = 0; i < 4; ++i)
      #pragma unroll
      for (int j = 0; j < 4; ++j)
        acc[i][j] = (f32x4){0.f, 0.f, 0.f, 0.f};
    #pragma unroll
    for (int ks = 0; ks < 4; ++ks){
      bf16x8 bfr[4];
      #pragma unroll
      for (int j = 0; j < 4; ++j){
        int col = wc + j*16 + l16;
        bfr[j] = __builtin_bit_cast(bf16x8, sK[col*16 + ((ks*4 + quad) ^ l16)]);
      }
      #pragma unroll
      for (int i = 0; i < 4; ++i)
        #pragma unroll
        for (int j = 0; j < 4; ++j)
          acc[i][j] = __builtin_amdgcn_mfma_f32_16x16x32_bf16(a[i][ks], bfr[j], acc[i][j], 0, 0, 0);
    }
    // epilogue: C[row=i*16+quad*4+r][col=j*16+l16]
    #pragma unroll
    for (int i = 0; i < 4; ++i)
      #pragma unroll
      for (int j = 0; j < 4; ++j)
        #pragma unroll
        for (int r = 0; r < 4; ++r)
          rsum[i*4 + r] += __expf(acc[i][j][r] * INV_T);
  }
  // reduce over the 16 cols (l16 lanes) per quad, then atomic per row
  #pragma unroll
  for (int s = 0; s < 16; ++s){
    float v = rsum[s];
    v += __shfl_xor(v, 1, 64);
    v += __shfl_xor(v, 2, 64);
    v += __shfl_xor(v, 4, 64);
    v += __shfl_xor(v, 8, 64);
    if (l16 == 0){
      int row = r0 + wr + (s >> 2)*16 + quad*4 + (s & 3);
      atomicAdd(&rowsum[b*NN + row], v);
    }
  }
}

// Kernel C: subtract diag exp, log1p, mean
__global__ __launch_bounds__(256) void finalize_kernel(const unsigned short* __restrict__ qn,
                                                       const unsigned short* __restrict__ kn,
                                                       const float* __restrict__ rowsum,
                                                       float* __restrict__ out){
  int idx = blockIdx.x*256 + threadIdx.x;   // 0..16383 = b*N + n
  const uint4* q = reinterpret_cast<const uint4*>(qn + (size_t)idx*DD);
  const uint4* k = reinterpret_cast<const uint4*>(kn + (size_t)idx*DD);
  float dot = 0.f;   // chunk order permuted identically in q,k -> dot invariant
  #pragma unroll
  for (int c = 0; c < 16; ++c){
    uint4 uq = q[c], uk = k[c];
    unsigned aq[4] = {uq.x, uq.y, uq.z, uq.w};
    unsigned ak[4] = {uk.x, uk.y, uk.z, uk.w};
    #pragma unroll
    for (int p = 0; p < 4; ++p){
      float q0 = __uint_as_float(aq[p] << 16);
      float q1 = __uint_as_float(aq[p] & 0xffff0000u);
      float k0 = __uint_as_float(ak[p] << 16);
      float k1 = __uint_as_float(ak[p] & 0xffff0000u);
      dot = fmaf(q0, k0, dot);
      dot = fmaf(q1, k1, dot);
    }
  }
  float diag = __expf(dot * INV_T);
  float loss = log1pf(rowsum[idx] - diag);
  loss += __shfl_xor(loss, 1, 64);
  loss += __shfl_xor(loss, 2, 64);
  loss += __shfl_xor(loss, 4, 64);
  loss += __shfl_xor(loss, 8, 64);
  loss += __shfl_xor(loss, 16, 64);
  loss += __shfl_xor(loss, 32, 64);
  if ((threadIdx.x & 63) == 0)
    atomicAdd(out, loss * (1.f / (float)(NB*NN)));
}

extern "C" void kernel_launch(void* const* d_in, const int* in_sizes, int n_in,
                              void* d_out, int out_size, void* d_ws, size_t ws_size,
                              hipStream_t stream){
  const float* fq = (const float*)d_in[0];
  const float* fk = (const float*)d_in[1];
  unsigned short* qn = (unsigned short*)d_ws;                  // 4 MB bf16 [B][N][D] (chunk-swizzled)
  unsigned short* kn = qn + (size_t)NB*NN*DD;                  // 4 MB
  float* rowsum = (float*)(kn + (size_t)NB*NN*DD);             // 64 KB
  float* out = (float*)d_out;

  hipMemsetAsync(rowsum, 0, (size_t)NB*NN*sizeof(float), stream);
  hipMemsetAsync(out, 0, sizeof(float), stream);

  norm_kernel<<<dim3(NN/64, NB, 2), 256, 0, stream>>>(fq, fk, qn, kn);
  simexp_kernel<<<dim3(NN/128, 4, NB), 256, 0, stream>>>(qn, kn, rowsum);
  finalize_kernel<<<dim3(NB*NN/256), 256, 0, stream>>>(qn, kn, rowsum, out);
}